// Round 1
// baseline (224.154 us; speedup 1.0000x reference)
//
#include <hip/hip_runtime.h>
#include <hip/hip_bf16.h>
#include <stdint.h>

// Problem constants (B=2, T=2048, C=768, H=12, hd=64, block=64)
#define T_SEQ 2048
#define C_DIM 768
#define NH 12
#define HD 64
#define QKV_LD 2304

typedef __attribute__((ext_vector_type(8))) short short8;   // 8 bf16 (4 VGPR)
typedef __attribute__((ext_vector_type(4))) float f32x4;
typedef const __attribute__((address_space(1))) void* gas_ptr;
typedef __attribute__((address_space(3))) void* las_ptr;

static __device__ __forceinline__ unsigned short f2bf(float f) {
  union { float f; unsigned u; } c; c.f = f;
  unsigned u = c.u + 0x7fffu + ((c.u >> 16) & 1u);
  return (unsigned short)(u >> 16);
}

// ---------------- f32 -> bf16 cast (vectorized) ----------------
__global__ void cast_kernel(const float* __restrict__ in,
                            unsigned short* __restrict__ out, int n4) {
  int i = blockIdx.x * blockDim.x + threadIdx.x;
  int stride = gridDim.x * blockDim.x;
  for (; i < n4; i += stride) {
    float4 v = ((const float4*)in)[i];
    ushort4 o;
    o.x = f2bf(v.x); o.y = f2bf(v.y); o.z = f2bf(v.z); o.w = f2bf(v.w);
    ((ushort4*)out)[i] = o;
  }
}

// ---------------- GEMM C = A * B^T  (A:[M,K] bf16, B:[N,K] bf16) ----------------
// 128x128 tile, BK=32, 256 threads (4 waves, 2x2 of 64x64), m97 structure.
__device__ __forceinline__ void stage_tile(const unsigned short* g, int ld,
                                           unsigned short* ldsbase, int tid) {
#pragma unroll
  for (int p = 0; p < 2; ++p) {
    int j = p * 256 + tid;                 // 16B chunk index, 512 total
    int row = j >> 2, cc = (j & 3) << 3;   // 4 chunks per 32-elem row
    const unsigned short* ga = g + (size_t)row * ld + cc;
    unsigned short* la = ldsbase + p * 2048 + (tid >> 6) * 512;  // wave-uniform
    __builtin_amdgcn_global_load_lds((gas_ptr)ga, (las_ptr)la, 16, 0, 0);
  }
}

template <int EPI>   // 0: QKV epilogue (bf16 qkv + scaled Q + V^T), 1: f32 out
__launch_bounds__(256, 2)
__global__ void gemm_bt(const unsigned short* __restrict__ A,
                        const unsigned short* __restrict__ B,
                        int K,
                        unsigned short* __restrict__ obf,
                        unsigned short* __restrict__ vt,
                        float* __restrict__ ofp,
                        const float* __restrict__ sptr) {
  __shared__ __attribute__((aligned(16))) unsigned short lds[8192]; // A:0..4095, B:4096..8191
  int tid = threadIdx.x;
  int lane = tid & 63, wave = tid >> 6;
  int row0 = blockIdx.x * 128, col0 = blockIdx.y * 128;
  int wr = (wave >> 1) * 64, wc = (wave & 1) * 64;
  int la = lane & 15, lb = lane >> 4;
  f32x4 acc[4][4] = {};

  for (int k0 = 0; k0 < K; k0 += 32) {
    __syncthreads();
    stage_tile(A + (size_t)row0 * K + k0, K, lds, tid);
    stage_tile(B + (size_t)col0 * K + k0, K, lds + 4096, tid);
    __syncthreads();
    short8 af[4], bfr[4];
#pragma unroll
    for (int i = 0; i < 4; ++i)
      af[i] = *(const short8*)&lds[(wr + i * 16 + la) * 32 + lb * 8];
#pragma unroll
    for (int j = 0; j < 4; ++j)
      bfr[j] = *(const short8*)&lds[4096 + (wc + j * 16 + la) * 32 + lb * 8];
#pragma unroll
    for (int i = 0; i < 4; ++i)
#pragma unroll
      for (int j = 0; j < 4; ++j)
        acc[i][j] = __builtin_amdgcn_mfma_f32_16x16x32_bf16(af[i], bfr[j], acc[i][j], 0, 0, 0);
  }

  // epilogue: C/D layout col=lane&15, row=(lane>>4)*4+r  [m89-verified]
  float qs = 0.f;
  if (EPI == 0)
    qs = sptr[0] * 7.624618986159398f /*ln(2048)*/ * 0.125f /*1/sqrt(hd)*/
         * 1.4426950408889634f /*log2(e): exp2 domain*/;
#pragma unroll
  for (int i = 0; i < 4; ++i) {
    int gr0 = row0 + wr + i * 16 + lb * 4;
#pragma unroll
    for (int j = 0; j < 4; ++j) {
      int gc = col0 + wc + j * 16 + la;
#pragma unroll
      for (int r = 0; r < 4; ++r) {
        float v = acc[i][j][r];
        int rr = gr0 + r;
        if (EPI == 0) {
          if (gc < 768) {
            obf[(size_t)rr * QKV_LD + gc] = f2bf(v * qs);          // Q (pre-scaled)
          } else if (gc < 1536) {
            obf[(size_t)rr * QKV_LD + gc] = f2bf(v);               // K
          } else {
            int nh = gc - 1536; int h = nh >> 6, d = nh & 63;      // V -> V^T buf
            int b = rr >> 11, t = rr & 2047;
            vt[((size_t)(b * NH + h) * 64 + d) * T_SEQ + t] = f2bf(v);
          }
        } else {
          ofp[(size_t)rr * C_DIM + gc] = v;
        }
      }
    }
  }
}

// ---------------- Flash attention, block-causal n=64 (no elementwise mask) ----
// grid: (32 q-tiles reversed, B*H). 256 threads = 4 waves, each wave 16 q-rows.
__launch_bounds__(256, 2)
__global__ void attn_kernel(const unsigned short* __restrict__ qkv,
                            const unsigned short* __restrict__ vt,
                            unsigned short* __restrict__ yb) {
  __shared__ __attribute__((aligned(16))) unsigned short k_lds[4096];   // [64 k][64 d] swz
  __shared__ __attribute__((aligned(16))) unsigned short v_lds[4096];   // [64 d][64 t] swz
  __shared__ __attribute__((aligned(16))) unsigned short p_lds[4][1024];// per-wave [16 q][64 k] swz

  int tid = threadIdx.x, lane = tid & 63, wave = tid >> 6;
  int la = lane & 15, lb = lane >> 4;
  int qi = (int)gridDim.x - 1 - (int)blockIdx.x;   // heavy tiles first
  int bh = blockIdx.y;
  int b = bh / NH, h = bh - b * NH;

  // Q fragments in registers (A-operand: row=lane&15, k=(lane>>4)*8, 2 chunks of 32)
  const unsigned short* qbase =
      qkv + ((size_t)(b * T_SEQ + qi * 64 + wave * 16 + la)) * QKV_LD + h * HD;
  short8 qf[2];
  qf[0] = *(const short8*)(qbase + lb * 8);
  qf[1] = *(const short8*)(qbase + 32 + lb * 8);

  f32x4 y[4] = {};
  float m[4], lsum[4];
#pragma unroll
  for (int r = 0; r < 4; ++r) { m[r] = -INFINITY; lsum[r] = 0.f; }

  const unsigned short* kg0 = qkv + (size_t)b * T_SEQ * QKV_LD + 768 + h * HD;
  const unsigned short* vg0 = vt + (size_t)bh * 64 * T_SEQ;

  for (int kt = 0; kt <= qi; ++kt) {
    __syncthreads();
    // stage K [64][64] and V^T [64][64], XOR-swizzled rows (G4 fix for 128B rows)
#pragma unroll
    for (int p = 0; p < 2; ++p) {
      int row = p * 32 + (tid >> 3);
      int cb = (tid & 7) * 16;  // byte col within 128B row
      int swz = (row * 128 + cb) ^ ((row & 7) << 4);
      short8 kvv = *(const short8*)(kg0 + (size_t)(kt * 64 + row) * QKV_LD + (cb >> 1));
      *(short8*)((char*)k_lds + swz) = kvv;
      short8 vvv = *(const short8*)(vg0 + (size_t)row * T_SEQ + kt * 64 + (cb >> 1));
      *(short8*)((char*)v_lds + swz) = vvv;
    }
    __syncthreads();

    // S = Q K^T (pre-scaled, exp2 domain). S frag: col(k)=la, row(q)=4*lb+r
    f32x4 s[4] = {};
#pragma unroll
    for (int fk = 0; fk < 4; ++fk) {
      int row = fk * 16 + la;
#pragma unroll
      for (int ch = 0; ch < 2; ++ch) {
        int off = (row * 128 + ch * 64 + lb * 16) ^ ((row & 7) << 4);
        short8 kf = *(const short8*)((char*)k_lds + off);
        s[fk] = __builtin_amdgcn_mfma_f32_16x16x32_bf16(qf[ch], kf, s[fk], 0, 0, 0);
      }
    }

    // online softmax (wave-parallel: 16-lane xor-shuffle row reduce)
#pragma unroll
    for (int r = 0; r < 4; ++r) {
      float mx = fmaxf(fmaxf(s[0][r], s[1][r]), fmaxf(s[2][r], s[3][r]));
      mx = fmaxf(mx, __shfl_xor(mx, 1));
      mx = fmaxf(mx, __shfl_xor(mx, 2));
      mx = fmaxf(mx, __shfl_xor(mx, 4));
      mx = fmaxf(mx, __shfl_xor(mx, 8));
      float mn = fmaxf(m[r], mx);
      float fac = exp2f(m[r] - mn);
      float ps = 0.f;
#pragma unroll
      for (int fk = 0; fk < 4; ++fk) {
        float p = exp2f(s[fk][r] - mn);
        s[fk][r] = p;
        ps += p;
      }
      ps += __shfl_xor(ps, 1); ps += __shfl_xor(ps, 2);
      ps += __shfl_xor(ps, 4); ps += __shfl_xor(ps, 8);
      lsum[r] = lsum[r] * fac + ps;
      m[r] = mn;
#pragma unroll
      for (int fd = 0; fd < 4; ++fd) y[fd][r] *= fac;
    }

    // P -> per-wave LDS (bf16, swizzled u16 writes): relayout C-frag -> A-frag
    char* pw = (char*)p_lds[wave];
#pragma unroll
    for (int fk = 0; fk < 4; ++fk)
#pragma unroll
      for (int r = 0; r < 4; ++r) {
        int row = lb * 4 + r;
        int off = (row * 128 + (fk * 16 + la) * 2) ^ ((row & 7) << 4);
        *(unsigned short*)(pw + off) = f2bf(s[fk][r]);
      }

    // Y += P V : A-frags from p_lds (reused over fd), B-frags from v_lds
    short8 pa[2];
#pragma unroll
    for (int ch = 0; ch < 2; ++ch) {
      int off = (la * 128 + ch * 64 + lb * 16) ^ ((la & 7) << 4);
      pa[ch] = *(const short8*)(pw + off);
    }
#pragma unroll
    for (int fd = 0; fd < 4; ++fd) {
      int row = fd * 16 + la;
#pragma unroll
      for (int ch = 0; ch < 2; ++ch) {
        int off = (row * 128 + ch * 64 + lb * 16) ^ ((row & 7) << 4);
        short8 vf = *(const short8*)((char*)v_lds + off);
        y[fd] = __builtin_amdgcn_mfma_f32_16x16x32_bf16(pa[ch], vf, y[fd], 0, 0, 0);
      }
    }
  }

  // epilogue: y/l -> bf16 att-out [B*T][C]
#pragma unroll
  for (int fd = 0; fd < 4; ++fd)
#pragma unroll
    for (int r = 0; r < 4; ++r) {
      float v = y[fd][r] / lsum[r];
      int rowg = b * T_SEQ + qi * 64 + wave * 16 + lb * 4 + r;
      int colg = h * HD + fd * 16 + la;
      yb[(size_t)rowg * C_DIM + colg] = f2bf(v);
    }
}

// ---------------- launch ----------------
extern "C" void kernel_launch(void* const* d_in, const int* in_sizes, int n_in,
                              void* d_out, int out_size, void* d_ws, size_t ws_size,
                              hipStream_t stream) {
  const float* x = (const float*)d_in[0];        // [2,2048,768]
  const float* attn_w = (const float*)d_in[1];   // [2304,768]
  const float* proj_w = (const float*)d_in[2];   // [768,768]
  const float* s = (const float*)d_in[3];        // [1]
  float* out = (float*)d_out;                    // [2,2048,768] f32

  char* ws = (char*)d_ws;
  unsigned short* xb   = (unsigned short*)(ws);                    // 6,291,456 B
  unsigned short* wab  = (unsigned short*)(ws + 6291456);          // 3,538,944 B
  unsigned short* wpb  = (unsigned short*)(ws + 9830400);          // 1,179,648 B
  unsigned short* qkvb = (unsigned short*)(ws + 11010048);         // 18,874,368 B
  unsigned short* vtb  = (unsigned short*)(ws + 29884416);         // 6,291,456 B
  unsigned short* yb   = (unsigned short*)(ws + 36175872);         // 6,291,456 B
  // total 42,467,328 B

  cast_kernel<<<1024, 256, 0, stream>>>(x, xb, 3145728 / 4);
  cast_kernel<<<512, 256, 0, stream>>>(attn_w, wab, 1769472 / 4);
  cast_kernel<<<256, 256, 0, stream>>>(proj_w, wpb, 589824 / 4);

  // QKV: [4096,768] x [2304,768]^T
  gemm_bt<0><<<dim3(32, 18), 256, 0, stream>>>(xb, wab, 768, qkvb, vtb, nullptr, s);

  // attention: 32 q-tiles x 24 (b,h)
  attn_kernel<<<dim3(32, 24), 256, 0, stream>>>(qkvb, vtb, yb);

  // proj: [4096,768] x [768,768]^T -> f32 out
  gemm_bt<1><<<dim3(32, 6), 256, 0, stream>>>(yb, wpb, 768, nullptr, nullptr, out, nullptr);
}

// Round 3
// 208.809 us; speedup vs baseline: 1.0735x; 1.0735x over previous
//
#include <hip/hip_runtime.h>
#include <hip/hip_bf16.h>
#include <stdint.h>

// Problem constants (B=2, T=2048, C=768, H=12, hd=64, block=64)
#define T_SEQ 2048
#define C_DIM 768
#define NH 12
#define HD 64
#define QKV_LD 2304

typedef __attribute__((ext_vector_type(8))) short short8;   // 8 bf16 (4 VGPR)
typedef __attribute__((ext_vector_type(4))) float f32x4;
typedef const __attribute__((address_space(1))) void* gas_ptr;
typedef __attribute__((address_space(3))) void* las_ptr;

static __device__ __forceinline__ unsigned short f2bf(float f) {
  union { float f; unsigned u; } c; c.f = f;
  unsigned u = c.u + 0x7fffu + ((c.u >> 16) & 1u);
  return (unsigned short)(u >> 16);
}

// ---------------- fused f32 -> bf16 cast for all three inputs ----------------
__global__ void cast3_kernel(const float* __restrict__ a, int na4,
                             const float* __restrict__ b, int nb4,
                             const float* __restrict__ c, int nc4,
                             unsigned short* __restrict__ oa,
                             unsigned short* __restrict__ ob,
                             unsigned short* __restrict__ oc) {
  int i = blockIdx.x * blockDim.x + threadIdx.x;
  int stride = gridDim.x * blockDim.x;
  int total = na4 + nb4 + nc4;
  for (; i < total; i += stride) {
    const float4* src; ushort4* dst; int j;
    if (i < na4)            { src = (const float4*)a; dst = (ushort4*)oa; j = i; }
    else if (i < na4 + nb4) { src = (const float4*)b; dst = (ushort4*)ob; j = i - na4; }
    else                    { src = (const float4*)c; dst = (ushort4*)oc; j = i - na4 - nb4; }
    float4 v = src[j];
    ushort4 o;
    o.x = f2bf(v.x); o.y = f2bf(v.y); o.z = f2bf(v.z); o.w = f2bf(v.w);
    dst[j] = o;
  }
}

// ---------------- GEMM C = A * B^T  (A:[M,K] bf16, B:[N,K] bf16) ----------------
// BM x 128 tile, BK=32, 256 threads (4 waves, 2x2), m97 structure.
template <int NP>
__device__ __forceinline__ void stage_tile(const unsigned short* g, int ld,
                                           unsigned short* ldsbase, int tid) {
#pragma unroll
  for (int p = 0; p < NP; ++p) {
    int j = p * 256 + tid;                 // 16B chunk index
    int row = j >> 2, cc = (j & 3) << 3;   // 4 chunks per 32-elem row
    const unsigned short* ga = g + (size_t)row * ld + cc;
    unsigned short* la = ldsbase + p * 2048 + (tid >> 6) * 512;  // wave-uniform
    __builtin_amdgcn_global_load_lds((gas_ptr)ga, (las_ptr)la, 16, 0, 0);
  }
}

template <int BM, int EPI>   // EPI 0: QKV epilogue (bf16 qkv + scaled Q + V^T), 1: f32 out
__launch_bounds__(256, 2)
__global__ void gemm_bt(const unsigned short* __restrict__ A,
                        const unsigned short* __restrict__ B,
                        int K,
                        unsigned short* __restrict__ obf,
                        unsigned short* __restrict__ vt,
                        float* __restrict__ ofp,
                        const float* __restrict__ sptr) {
  constexpr int MI = BM / 32;
  __shared__ __attribute__((aligned(16))) unsigned short lds[BM * 32 + 4096];
  int tid = threadIdx.x;
  int lane = tid & 63, wave = tid >> 6;
  int row0 = blockIdx.x * BM, col0 = blockIdx.y * 128;
  int wr = (wave >> 1) * (BM / 2), wc = (wave & 1) * 64;
  int la = lane & 15, lb = lane >> 4;
  f32x4 acc[MI][4] = {};

  for (int k0 = 0; k0 < K; k0 += 32) {
    __syncthreads();
    stage_tile<BM / 64>(A + (size_t)row0 * K + k0, K, lds, tid);
    stage_tile<2>(B + (size_t)col0 * K + k0, K, lds + BM * 32, tid);
    __syncthreads();
    short8 af[MI], bfr[4];
#pragma unroll
    for (int i = 0; i < MI; ++i)
      af[i] = *(const short8*)&lds[(wr + i * 16 + la) * 32 + lb * 8];
#pragma unroll
    for (int j = 0; j < 4; ++j)
      bfr[j] = *(const short8*)&lds[BM * 32 + (wc + j * 16 + la) * 32 + lb * 8];
#pragma unroll
    for (int i = 0; i < MI; ++i)
#pragma unroll
      for (int j = 0; j < 4; ++j)
        acc[i][j] = __builtin_amdgcn_mfma_f32_16x16x32_bf16(af[i], bfr[j], acc[i][j], 0, 0, 0);
  }

  // epilogue: C/D layout col=lane&15, row=(lane>>4)*4+r  [m89-verified]
  float qs = 0.f;
  if (EPI == 0)
    qs = sptr[0] * 7.624618986159398f /*ln(2048)*/ * 0.125f /*1/sqrt(hd)*/
         * 1.4426950408889634f /*log2(e): exp2 domain*/;
#pragma unroll
  for (int i = 0; i < MI; ++i) {
    int gr0 = row0 + wr + i * 16 + lb * 4;
#pragma unroll
    for (int j = 0; j < 4; ++j) {
      int gc = col0 + wc + j * 16 + la;
#pragma unroll
      for (int r = 0; r < 4; ++r) {
        float v = acc[i][j][r];
        int rr = gr0 + r;
        if (EPI == 0) {
          if (gc < 768) {
            obf[(size_t)rr * QKV_LD + gc] = f2bf(v * qs);          // Q (pre-scaled)
          } else if (gc < 1536) {
            obf[(size_t)rr * QKV_LD + gc] = f2bf(v);               // K
          } else {
            int nh = gc - 1536; int h = nh >> 6, d = nh & 63;      // V -> V^T buf
            int b = rr >> 11, t = rr & 2047;
            vt[((size_t)(b * NH + h) * 64 + d) * T_SEQ + t] = f2bf(v);
          }
        } else {
          ofp[(size_t)rr * C_DIM + gc] = v;
        }
      }
    }
  }
}

// ---------------- Flash attention, block-causal n=64 ----------------
// grid: (32 q-tiles reversed, B*H). 256 threads = 4 waves, each wave 16 q-rows.
// Double-buffered K/V via global_load_lds with pre-swizzled global source
// (rule 21: linear LDS dest + inverse-swizzled source == swizzled layout),
// counted vmcnt(4), raw s_barrier. RACE FIX (round 2 bug): raw s_barrier has
// NO memory semantics in LLVM -> compiler hoisted buf[cur] ds_reads above
// barrier B, reading rows other waves hadn't staged yet. Pin with asm memory
// clobbers on both sides + sched_barrier(0); HW ordering via counted vmcnt.
__device__ __forceinline__ void attn_stage(const unsigned short* kg,
                                           const unsigned short* vg,
                                           char* kbuf, int wave, int lane) {
  int l3 = lane >> 3;
  int cg = ((lane & 7) ^ l3) << 4;  // swizzled source chunk byte offset
#pragma unroll
  for (int q = 0; q < 2; ++q) {
    int rk = q * 32 + wave * 8 + l3;                 // row within 64-row tile
    const unsigned short* ka = kg + (size_t)rk * QKV_LD + (cg >> 1);
    char* kl = kbuf + (q * 32 + wave * 8) * 128;     // wave-uniform dest
    __builtin_amdgcn_global_load_lds((gas_ptr)ka, (las_ptr)kl, 16, 0, 0);
    const unsigned short* va = vg + (size_t)rk * T_SEQ + (cg >> 1);
    char* vl = kbuf + 8192 + (q * 32 + wave * 8) * 128;
    __builtin_amdgcn_global_load_lds((gas_ptr)va, (las_ptr)vl, 16, 0, 0);
  }
}

__launch_bounds__(256, 4)
__global__ void attn_kernel(const unsigned short* __restrict__ qkv,
                            const unsigned short* __restrict__ vt,
                            unsigned short* __restrict__ yb) {
  // buf c: K at c*16384, V at c*16384+8192; per-wave P at 32768+wave*2048
  __shared__ __attribute__((aligned(16))) char smem[2 * 16384 + 8192];

  int tid = threadIdx.x, lane = tid & 63, wave = tid >> 6;
  int la = lane & 15, lb = lane >> 4;
  int qi = (int)gridDim.x - 1 - (int)blockIdx.x;   // heavy tiles first
  int bh = blockIdx.y;
  int b = bh / NH, h = bh - b * NH;

  // Q fragments in registers (A-operand: row=lane&15, k=(lane>>4)*8)
  const unsigned short* qbase =
      qkv + ((size_t)(b * T_SEQ + qi * 64 + wave * 16 + la)) * QKV_LD + h * HD;
  short8 qf0 = *(const short8*)(qbase + lb * 8);
  short8 qf1 = *(const short8*)(qbase + 32 + lb * 8);
  // force Q materialization NOW so compiler's waitcnt for it doesn't drain
  // the in-loop prefetch queue
  asm volatile("" :: "v"(qf0), "v"(qf1));

  f32x4 y[4] = {};
  float m[4], lsum[4];
#pragma unroll
  for (int r = 0; r < 4; ++r) { m[r] = -INFINITY; lsum[r] = 0.f; }

  const unsigned short* kg0 = qkv + (size_t)b * T_SEQ * QKV_LD + 768 + h * HD;
  const unsigned short* vg0 = vt + (size_t)bh * 64 * T_SEQ;
  char* pw = smem + 32768 + wave * 2048;

  attn_stage(kg0, vg0, smem, wave, lane);   // prologue: tile 0 -> buf 0
  int cur = 0;

  for (int kt = 0; kt <= qi; ++kt) {
    // pin prior-iteration LDS reads above barrier A (compiler fence)
    asm volatile("" ::: "memory");
    // barrier A: all waves done READING buf[cur^1] (iter kt-1's compute)
    __builtin_amdgcn_s_barrier();
    if (kt < qi) {
      attn_stage(kg0 + (size_t)(kt + 1) * 64 * QKV_LD, vg0 + (kt + 1) * 64,
                 smem + ((cur ^ 1) * 16384), wave, lane);
      asm volatile("s_waitcnt vmcnt(4)" ::: "memory");  // tile kt landed; kt+1 in flight
    } else {
      asm volatile("s_waitcnt vmcnt(0)" ::: "memory");
    }
    // barrier B: buf[cur] visible from ALL waves (each staged 8 of 64 rows)
    __builtin_amdgcn_s_barrier();
    // pin compute-phase LDS reads BELOW barrier B (the round-2 race)
    asm volatile("" ::: "memory");
    __builtin_amdgcn_sched_barrier(0);

    char* kl = smem + cur * 16384;
    char* vl = kl + 8192;

    // S = Q K^T (pre-scaled, exp2 domain). S frag: col(k)=la, row(q)=4*lb+r
    f32x4 s[4] = {};
    __builtin_amdgcn_s_setprio(1);
#pragma unroll
    for (int fk = 0; fk < 4; ++fk) {
      int row = fk * 16 + la;
      {
        int off = (row * 128 + 0 * 64 + lb * 16) ^ ((row & 7) << 4);
        short8 kf = *(const short8*)(kl + off);
        s[fk] = __builtin_amdgcn_mfma_f32_16x16x32_bf16(qf0, kf, s[fk], 0, 0, 0);
      }
      {
        int off = (row * 128 + 1 * 64 + lb * 16) ^ ((row & 7) << 4);
        short8 kf = *(const short8*)(kl + off);
        s[fk] = __builtin_amdgcn_mfma_f32_16x16x32_bf16(qf1, kf, s[fk], 0, 0, 0);
      }
    }
    __builtin_amdgcn_s_setprio(0);

    // online softmax (wave-parallel: 16-lane xor-shuffle row reduce)
#pragma unroll
    for (int r = 0; r < 4; ++r) {
      float mx = fmaxf(fmaxf(s[0][r], s[1][r]), fmaxf(s[2][r], s[3][r]));
      mx = fmaxf(mx, __shfl_xor(mx, 1));
      mx = fmaxf(mx, __shfl_xor(mx, 2));
      mx = fmaxf(mx, __shfl_xor(mx, 4));
      mx = fmaxf(mx, __shfl_xor(mx, 8));
      float mn = fmaxf(m[r], mx);
      float fac = exp2f(m[r] - mn);
      float ps = 0.f;
#pragma unroll
      for (int fk = 0; fk < 4; ++fk) {
        float p = exp2f(s[fk][r] - mn);
        s[fk][r] = p;
        ps += p;
      }
      ps += __shfl_xor(ps, 1); ps += __shfl_xor(ps, 2);
      ps += __shfl_xor(ps, 4); ps += __shfl_xor(ps, 8);
      lsum[r] = lsum[r] * fac + ps;
      m[r] = mn;
#pragma unroll
      for (int fd = 0; fd < 4; ++fd) y[fd][r] *= fac;
    }

    // P -> per-wave LDS (bf16, swizzled u16 writes): relayout C-frag -> A-frag
#pragma unroll
    for (int fk = 0; fk < 4; ++fk)
#pragma unroll
      for (int r = 0; r < 4; ++r) {
        int row = lb * 4 + r;
        int off = (row * 128 + (fk * 16 + la) * 2) ^ ((row & 7) << 4);
        *(unsigned short*)(pw + off) = f2bf(s[fk][r]);
      }

    // Y += P V : A-frags from p_lds (reused over fd), B-frags from v_lds
    short8 pa[2];
#pragma unroll
    for (int ch = 0; ch < 2; ++ch) {
      int off = (la * 128 + ch * 64 + lb * 16) ^ ((la & 7) << 4);
      pa[ch] = *(const short8*)(pw + off);
    }
    __builtin_amdgcn_s_setprio(1);
#pragma unroll
    for (int fd = 0; fd < 4; ++fd) {
      int row = fd * 16 + la;
#pragma unroll
      for (int ch = 0; ch < 2; ++ch) {
        int off = (row * 128 + ch * 64 + lb * 16) ^ ((row & 7) << 4);
        short8 vf = *(const short8*)(vl + off);
        y[fd] = __builtin_amdgcn_mfma_f32_16x16x32_bf16(pa[ch], vf, y[fd], 0, 0, 0);
      }
    }
    __builtin_amdgcn_s_setprio(0);

    cur ^= 1;
  }

  // epilogue: y/l -> bf16 att-out [B*T][C]
#pragma unroll
  for (int fd = 0; fd < 4; ++fd)
#pragma unroll
    for (int r = 0; r < 4; ++r) {
      float v = y[fd][r] / lsum[r];
      int rowg = b * T_SEQ + qi * 64 + wave * 16 + lb * 4 + r;
      int colg = h * HD + fd * 16 + la;
      yb[(size_t)rowg * C_DIM + colg] = f2bf(v);
    }
}

// ---------------- launch ----------------
extern "C" void kernel_launch(void* const* d_in, const int* in_sizes, int n_in,
                              void* d_out, int out_size, void* d_ws, size_t ws_size,
                              hipStream_t stream) {
  const float* x = (const float*)d_in[0];        // [2,2048,768]
  const float* attn_w = (const float*)d_in[1];   // [2304,768]
  const float* proj_w = (const float*)d_in[2];   // [768,768]
  const float* s = (const float*)d_in[3];        // [1]
  float* out = (float*)d_out;                    // [2,2048,768] f32

  char* ws = (char*)d_ws;
  unsigned short* xb   = (unsigned short*)(ws);                    // 6,291,456 B
  unsigned short* wab  = (unsigned short*)(ws + 6291456);          // 3,538,944 B
  unsigned short* wpb  = (unsigned short*)(ws + 9830400);          // 1,179,648 B
  unsigned short* qkvb = (unsigned short*)(ws + 11010048);         // 18,874,368 B
  unsigned short* vtb  = (unsigned short*)(ws + 29884416);         // 6,291,456 B
  unsigned short* yb   = (unsigned short*)(ws + 36175872);         // 6,291,456 B
  // total 42,467,328 B

  cast3_kernel<<<2048, 256, 0, stream>>>(x, 3145728 / 4, attn_w, 1769472 / 4,
                                         proj_w, 589824 / 4, xb, wab, wpb);

  // QKV: [4096,768] x [2304,768]^T
  gemm_bt<128, 0><<<dim3(32, 18), 256, 0, stream>>>(xb, wab, 768, qkvb, vtb, nullptr, s);

  // attention: 32 q-tiles x 24 (b,h)
  attn_kernel<<<dim3(32, 24), 256, 0, stream>>>(qkvb, vtb, yb);

  // proj: [4096,768] x [768,768]^T -> f32 out (BM=64: 384 blocks, fixes underfill)
  gemm_bt<64, 1><<<dim3(64, 6), 256, 0, stream>>>(yb, wpb, 768, nullptr, nullptr, out, nullptr);
}

// Round 5
// 163.696 us; speedup vs baseline: 1.3693x; 1.2756x over previous
//
#include <hip/hip_runtime.h>
#include <hip/hip_bf16.h>
#include <stdint.h>

// Problem constants (B=2, T=2048, C=768, H=12, hd=64, block=64)
#define T_SEQ 2048
#define C_DIM 768
#define NH 12
#define HD 64
#define QK_LD 1536   // packed Q|K buffer leading dim

typedef __attribute__((ext_vector_type(8))) short short8;   // 8 bf16 (4 VGPR)
typedef __attribute__((ext_vector_type(4))) float f32x4;
typedef const __attribute__((address_space(1))) void* gas_ptr;
typedef __attribute__((address_space(3))) void* las_ptr;

static __device__ __forceinline__ unsigned short f2bf(float f) {
  union { float f; unsigned u; } c; c.f = f;
  unsigned u = c.u + 0x7fffu + ((c.u >> 16) & 1u);
  return (unsigned short)(u >> 16);
}

// ---------------- fused f32 -> bf16 cast for all three inputs ----------------
__global__ void cast3_kernel(const float* __restrict__ a, int na4,
                             const float* __restrict__ b, int nb4,
                             const float* __restrict__ c, int nc4,
                             unsigned short* __restrict__ oa,
                             unsigned short* __restrict__ ob,
                             unsigned short* __restrict__ oc) {
  int i = blockIdx.x * blockDim.x + threadIdx.x;
  int stride = gridDim.x * blockDim.x;
  int total = na4 + nb4 + nc4;
  for (; i < total; i += stride) {
    const float4* src; ushort4* dst; int j;
    if (i < na4)            { src = (const float4*)a; dst = (ushort4*)oa; j = i; }
    else if (i < na4 + nb4) { src = (const float4*)b; dst = (ushort4*)ob; j = i - na4; }
    else                    { src = (const float4*)c; dst = (ushort4*)oc; j = i - na4 - nb4; }
    float4 v = src[j];
    ushort4 o;
    o.x = f2bf(v.x); o.y = f2bf(v.y); o.z = f2bf(v.z); o.w = f2bf(v.w);
    dst[j] = o;
  }
}

// ---------------- zero two f32 ranges (yp slot1 + lsp slot1) ----------------
__global__ void zero2_kernel(float4* __restrict__ a, int n4a,
                             float4* __restrict__ b, int n4b) {
  int i = blockIdx.x * blockDim.x + threadIdx.x;
  int stride = gridDim.x * blockDim.x;
  float4 z = {0.f, 0.f, 0.f, 0.f};
  for (int j = i; j < n4a; j += stride) a[j] = z;
  for (int j = i; j < n4b; j += stride) b[j] = z;
}

// ---------------- GEMM C = A * B^T  (A:[M,K] bf16, B:[N,K] bf16) ----------------
// BM x 128 tile, BK=32, 256 threads (4 waves, 2x2), m97 structure.
template <int NP>
__device__ __forceinline__ void stage_tile(const unsigned short* g, int ld,
                                           unsigned short* ldsbase, int tid) {
#pragma unroll
  for (int p = 0; p < NP; ++p) {
    int j = p * 256 + tid;                 // 16B chunk index
    int row = j >> 2, cc = (j & 3) << 3;   // 4 chunks per 32-elem row
    const unsigned short* ga = g + (size_t)row * ld + cc;
    unsigned short* la = ldsbase + p * 2048 + (tid >> 6) * 512;  // wave-uniform
    __builtin_amdgcn_global_load_lds((gas_ptr)ga, (las_ptr)la, 16, 0, 0);
  }
}

// EPI 0: QKV epilogue — Q(scaled)/K -> qkb [4096][1536]; V -> LDS-transposed V^T
// EPI 1: f32 out
template <int BM, int EPI>
__launch_bounds__(256, 2)
__global__ void gemm_bt(const unsigned short* __restrict__ A,
                        const unsigned short* __restrict__ B,
                        int K,
                        unsigned short* __restrict__ obf,
                        unsigned short* __restrict__ vt,
                        float* __restrict__ ofp,
                        const float* __restrict__ sptr) {
  constexpr int MI = BM / 32;
  constexpr int LDS_SH = BM * 32 + 4096;                   // staging, shorts
  constexpr int TR_SH = (EPI == 0) ? 128 * 130 : 0;        // transpose buf, shorts
  constexpr int TOT = LDS_SH > TR_SH ? LDS_SH : TR_SH;
  __shared__ __attribute__((aligned(16))) unsigned short smem[TOT];
  unsigned short* lds = smem;
  int tid = threadIdx.x;
  int lane = tid & 63, wave = tid >> 6;
  int row0 = blockIdx.x * BM, col0 = blockIdx.y * 128;
  int wr = (wave >> 1) * (BM / 2), wc = (wave & 1) * 64;
  int la = lane & 15, lb = lane >> 4;
  f32x4 acc[MI][4] = {};

  for (int k0 = 0; k0 < K; k0 += 32) {
    __syncthreads();
    stage_tile<BM / 64>(A + (size_t)row0 * K + k0, K, lds, tid);
    stage_tile<2>(B + (size_t)col0 * K + k0, K, lds + BM * 32, tid);
    __syncthreads();
    short8 af[MI], bfr[4];
#pragma unroll
    for (int i = 0; i < MI; ++i)
      af[i] = *(const short8*)&lds[(wr + i * 16 + la) * 32 + lb * 8];
#pragma unroll
    for (int j = 0; j < 4; ++j)
      bfr[j] = *(const short8*)&lds[BM * 32 + (wc + j * 16 + la) * 32 + lb * 8];
#pragma unroll
    for (int i = 0; i < MI; ++i)
#pragma unroll
      for (int j = 0; j < 4; ++j)
        acc[i][j] = __builtin_amdgcn_mfma_f32_16x16x32_bf16(af[i], bfr[j], acc[i][j], 0, 0, 0);
  }

  // epilogue: C/D layout col=lane&15, row=(lane>>4)*4+r  [m89-verified]
  if (EPI == 0 && col0 >= 1536) {
    // ---- V block: transpose via padded LDS, coalesced V^T writes ----
    __syncthreads();   // all waves done reading staging lds (aliased by tr)
#pragma unroll
    for (int i = 0; i < MI; ++i)
#pragma unroll
      for (int j = 0; j < 4; ++j)
#pragma unroll
        for (int r = 0; r < 4; ++r)
          smem[(wr + i * 16 + lb * 4 + r) * 130 + (wc + j * 16 + la)] =
              f2bf(acc[i][j][r]);
    __syncthreads();
    int bb = row0 >> 11, t0 = row0 & 2047;
    int cl = tid >> 1, half = tid & 1;                 // cl: 0..127 col of C
    int vcol = col0 - 1536 + cl;
    int h = vcol >> 6, d = vcol & 63;
    unsigned short* dst =
        vt + ((size_t)(bb * NH + h) * 64 + d) * T_SEQ + t0 + half * 64;
#pragma unroll
    for (int j = 0; j < 8; ++j) {
      short8 v8;
#pragma unroll
      for (int e = 0; e < 8; ++e)
        v8[e] = (short)smem[(half * 64 + j * 8 + e) * 130 + cl];
      *(short8*)(dst + j * 8) = v8;
    }
    return;
  }

  float qs = 0.f;
  if (EPI == 0)
    qs = sptr[0] * 7.624618986159398f /*ln(2048)*/ * 0.125f /*1/sqrt(hd)*/
         * 1.4426950408889634f /*log2(e): exp2 domain*/;
#pragma unroll
  for (int i = 0; i < MI; ++i) {
    int gr0 = row0 + wr + i * 16 + lb * 4;
#pragma unroll
    for (int j = 0; j < 4; ++j) {
      int gc = col0 + wc + j * 16 + la;
#pragma unroll
      for (int r = 0; r < 4; ++r) {
        float v = acc[i][j][r];
        int rr = gr0 + r;
        if (EPI == 0) {
          obf[(size_t)rr * QK_LD + gc] = f2bf(gc < 768 ? v * qs : v);
        } else {
          ofp[(size_t)rr * C_DIM + gc] = v;
        }
      }
    }
  }
}

// ---------------- Flash attention, block-causal n=64, split-K chunks --------
// No max subtraction (exp2-domain scores bounded ~|15|: f32-safe); lsum
// deferred to one post-loop reduce. Partials (y, lsum) -> 2 slots, summed by
// norm_kernel. Grid: (48, 24): per bh, qi 0..15 -> 1 chunk, qi 16..31 -> 2.
__device__ __forceinline__ void attn_stage(const unsigned short* kg,
                                           const unsigned short* vg,
                                           char* kbuf, int wave, int lane) {
  int l3 = lane >> 3;
  int cg = ((lane & 7) ^ l3) << 4;  // swizzled source chunk byte offset
#pragma unroll
  for (int q = 0; q < 2; ++q) {
    int rk = q * 32 + wave * 8 + l3;                 // row within 64-row tile
    const unsigned short* ka = kg + (size_t)rk * QK_LD + (cg >> 1);
    char* kl = kbuf + (q * 32 + wave * 8) * 128;     // wave-uniform dest
    __builtin_amdgcn_global_load_lds((gas_ptr)ka, (las_ptr)kl, 16, 0, 0);
    const unsigned short* va = vg + (size_t)rk * T_SEQ + (cg >> 1);
    char* vl = kbuf + 8192 + (q * 32 + wave * 8) * 128;
    __builtin_amdgcn_global_load_lds((gas_ptr)va, (las_ptr)vl, 16, 0, 0);
  }
}

__launch_bounds__(256, 4)
__global__ void attn_kernel(const unsigned short* __restrict__ qkb,
                            const unsigned short* __restrict__ vt,
                            float* __restrict__ yp,     // [2][24][2048][64]
                            float* __restrict__ lsp) {  // [2][24][2048]
  __shared__ __attribute__((aligned(16))) char smem[2 * 16384 + 8192];

  int tid = threadIdx.x, lane = tid & 63, wave = tid >> 6;
  int la = lane & 15, lb = lane >> 4;
  int xx = 47 - (int)blockIdx.x;   // heavy chunks dispatch first
  int qi, cch;
  if (xx < 16) { qi = xx; cch = 0; }
  else         { int t = xx - 16; qi = 16 + (t >> 1); cch = t & 1; }
  int kt0 = cch * 16;
  int kt1 = min(qi, kt0 + 15);
  int bh = blockIdx.y;
  int b = bh / NH, h = bh - b * NH;

  // Q fragments in registers (A-operand: row=lane&15, k=(lane>>4)*8)
  const unsigned short* qbase =
      qkb + ((size_t)(b * T_SEQ + qi * 64 + wave * 16 + la)) * QK_LD + h * HD;
  short8 qf0 = *(const short8*)(qbase + lb * 8);
  short8 qf1 = *(const short8*)(qbase + 32 + lb * 8);
  asm volatile("" :: "v"(qf0), "v"(qf1));   // materialize before prefetch loop

  f32x4 y[4] = {};
  float ls[4] = {0.f, 0.f, 0.f, 0.f};

  const unsigned short* kg0 = qkb + (size_t)b * T_SEQ * QK_LD + 768 + h * HD;
  const unsigned short* vg0 = vt + (size_t)bh * 64 * T_SEQ;
  char* pw = smem + 32768 + wave * 2048;

  attn_stage(kg0 + (size_t)kt0 * 64 * QK_LD, vg0 + kt0 * 64, smem, wave, lane);
  int cur = 0;

  for (int kt = kt0; kt <= kt1; ++kt) {
    asm volatile("" ::: "memory");
    __builtin_amdgcn_s_barrier();            // done reading buf[cur^1]
    if (kt < kt1) {
      attn_stage(kg0 + (size_t)(kt + 1) * 64 * QK_LD, vg0 + (kt + 1) * 64,
                 smem + ((cur ^ 1) * 16384), wave, lane);
      asm volatile("s_waitcnt vmcnt(4)" ::: "memory");
    } else {
      asm volatile("s_waitcnt vmcnt(0)" ::: "memory");
    }
    __builtin_amdgcn_s_barrier();            // buf[cur] visible from all waves
    asm volatile("" ::: "memory");
    __builtin_amdgcn_sched_barrier(0);

    char* kl = smem + cur * 16384;
    char* vl = kl + 8192;

    // S = Q K^T (pre-scaled, exp2 domain). S frag: col(k)=la, row(q)=4*lb+r
    f32x4 s[4] = {};
    __builtin_amdgcn_s_setprio(1);
#pragma unroll
    for (int fk = 0; fk < 4; ++fk) {
      int row = fk * 16 + la;
      {
        int off = (row * 128 + 0 * 64 + lb * 16) ^ ((row & 7) << 4);
        short8 kf = *(const short8*)(kl + off);
        s[fk] = __builtin_amdgcn_mfma_f32_16x16x32_bf16(qf0, kf, s[fk], 0, 0, 0);
      }
      {
        int off = (row * 128 + 1 * 64 + lb * 16) ^ ((row & 7) << 4);
        short8 kf = *(const short8*)(kl + off);
        s[fk] = __builtin_amdgcn_mfma_f32_16x16x32_bf16(qf1, kf, s[fk], 0, 0, 0);
      }
    }
    __builtin_amdgcn_s_setprio(0);

    // p = exp2(S); accumulate per-lane lsum; write P to per-wave LDS
#pragma unroll
    for (int fk = 0; fk < 4; ++fk)
#pragma unroll
      for (int r = 0; r < 4; ++r) {
        float p = __builtin_amdgcn_exp2f(s[fk][r]);
        s[fk][r] = p;
        ls[r] += p;
        int row = lb * 4 + r;
        int off = (row * 128 + (fk * 16 + la) * 2) ^ ((row & 7) << 4);
        *(unsigned short*)(pw + off) = f2bf(p);
      }

    // Y += P V : A-frags from p_lds, B-frags from v_lds
    short8 pa[2];
#pragma unroll
    for (int ch = 0; ch < 2; ++ch) {
      int off = (la * 128 + ch * 64 + lb * 16) ^ ((la & 7) << 4);
      pa[ch] = *(const short8*)(pw + off);
    }
    __builtin_amdgcn_s_setprio(1);
#pragma unroll
    for (int fd = 0; fd < 4; ++fd) {
      int row = fd * 16 + la;
#pragma unroll
      for (int ch = 0; ch < 2; ++ch) {
        int off = (row * 128 + ch * 64 + lb * 16) ^ ((row & 7) << 4);
        short8 vf = *(const short8*)(vl + off);
        y[fd] = __builtin_amdgcn_mfma_f32_16x16x32_bf16(pa[ch], vf, y[fd], 0, 0, 0);
      }
    }
    __builtin_amdgcn_s_setprio(0);

    cur ^= 1;
  }

  // post-loop: reduce lsum over la (16 lanes), write f32 partials to slot cch
  size_t slotbase = (size_t)cch * (24 * 2048);
#pragma unroll
  for (int r = 0; r < 4; ++r) {
    float v = ls[r];
    v += __shfl_xor(v, 1); v += __shfl_xor(v, 2);
    v += __shfl_xor(v, 4); v += __shfl_xor(v, 8);
    ls[r] = v;
  }
  int trow = qi * 64 + wave * 16 + lb * 4;   // + r
  if (la == 0) {
#pragma unroll
    for (int r = 0; r < 4; ++r)
      lsp[slotbase + (size_t)bh * 2048 + trow + r] = ls[r];
  }
  float* ydst = yp + (slotbase + (size_t)bh * 2048) * 64;
#pragma unroll
  for (int fd = 0; fd < 4; ++fd)
#pragma unroll
    for (int r = 0; r < 4; ++r)
      ydst[(size_t)(trow + r) * 64 + fd * 16 + la] = y[fd][r];
}

// ---------------- normalize + pack: yb = bf16((yp0+yp1)/(l0+l1)) -----------
__global__ void norm_kernel(const float* __restrict__ yp,
                            const float* __restrict__ lsp,
                            unsigned short* __restrict__ yb) {
  int gid = blockIdx.x * blockDim.x + threadIdx.x;  // 24*2048*16
  int dq = gid & 15;
  int row = gid >> 4;            // bh*2048 + t
  int bh = row >> 11, t = row & 2047;
  int b = bh / NH, h = bh - b * NH;
  float denom = lsp[row] + lsp[24 * 2048 + row];
  float inv = 1.0f / denom;
  float4 y0 = ((const float4*)yp)[row * 16 + dq];
  float4 y1 = ((const float4*)yp)[(24 * 2048 * 16) + row * 16 + dq];
  ushort4 o;
  o.x = f2bf((y0.x + y1.x) * inv);
  o.y = f2bf((y0.y + y1.y) * inv);
  o.z = f2bf((y0.z + y1.z) * inv);
  o.w = f2bf((y0.w + y1.w) * inv);
  ((ushort4*)yb)[(size_t)(b * T_SEQ + t) * 192 + h * 16 + dq] = o;
}

// ---------------- launch ----------------
extern "C" void kernel_launch(void* const* d_in, const int* in_sizes, int n_in,
                              void* d_out, int out_size, void* d_ws, size_t ws_size,
                              hipStream_t stream) {
  const float* x = (const float*)d_in[0];        // [2,2048,768]
  const float* attn_w = (const float*)d_in[1];   // [2304,768]
  const float* proj_w = (const float*)d_in[2];   // [768,768]
  const float* s = (const float*)d_in[3];        // [1]
  float* out = (float*)d_out;                    // [2,2048,768] f32

  char* ws = (char*)d_ws;
  unsigned short* xb  = (unsigned short*)(ws);                    //  6,291,456
  unsigned short* wab = (unsigned short*)(ws + 6291456);          //  3,538,944
  unsigned short* wpb = (unsigned short*)(ws + 9830400);          //  1,179,648
  unsigned short* qkb = (unsigned short*)(ws + 11010048);         // 12,582,912
  unsigned short* vtb = (unsigned short*)(ws + 23592960);         //  6,291,456
  unsigned short* yb  = (unsigned short*)(ws + 29884416);         //  6,291,456
  float*          yp  = (float*)(ws + 36175872);                  // 25,165,824 (2 slots)
  float*          lsp = (float*)(ws + 61341696);                  //    393,216 (2 slots)
  // total 61,734,912 B

  cast3_kernel<<<2048, 256, 0, stream>>>(x, 3145728 / 4, attn_w, 1769472 / 4,
                                         proj_w, 589824 / 4, xb, wab, wpb);

  // zero slot-1 partials (slot 0 always fully written)
  zero2_kernel<<<1024, 256, 0, stream>>>((float4*)(yp + 24 * 2048 * 64), 786432,
                                         (float4*)(lsp + 24 * 2048), 12288);

  // QKV: [4096,768] x [2304,768]^T -> Q/K packed (LD 1536) + V^T
  gemm_bt<128, 0><<<dim3(32, 18), 256, 0, stream>>>(xb, wab, 768, qkb, vtb, nullptr, s);

  // attention: split-K chunks, 48 x 24 blocks
  attn_kernel<<<dim3(48, 24), 256, 0, stream>>>(qkb, vtb, yp, lsp);

  // combine partials -> yb bf16 [4096][768]
  norm_kernel<<<3072, 256, 0, stream>>>(yp, lsp, yb);

  // proj: [4096,768] x [768,768]^T -> f32 out
  gemm_bt<64, 1><<<dim3(64, 6), 256, 0, stream>>>(yb, wpb, 768, nullptr, nullptr, out, nullptr);
}

// Round 6
// 149.258 us; speedup vs baseline: 1.5018x; 1.0967x over previous
//
#include <hip/hip_runtime.h>
#include <hip/hip_bf16.h>
#include <stdint.h>

// Problem constants (B=2, T=2048, C=768, H=12, hd=64, block=64)
#define T_SEQ 2048
#define C_DIM 768
#define NH 12
#define HD 64
#define QK_LD 1536   // packed Q|K buffer leading dim

typedef __attribute__((ext_vector_type(8))) short short8;   // 8 bf16 (4 VGPR)
typedef __attribute__((ext_vector_type(4))) float f32x4;
typedef const __attribute__((address_space(1))) void* gas_ptr;
typedef __attribute__((address_space(3))) void* las_ptr;

static __device__ __forceinline__ unsigned short f2bf(float f) {
  union { float f; unsigned u; } c; c.f = f;
  unsigned u = c.u + 0x7fffu + ((c.u >> 16) & 1u);
  return (unsigned short)(u >> 16);
}

// ---------------- fused f32 -> bf16 cast for all three inputs ----------------
__global__ void cast3_kernel(const float* __restrict__ a, int na4,
                             const float* __restrict__ b, int nb4,
                             const float* __restrict__ c, int nc4,
                             unsigned short* __restrict__ oa,
                             unsigned short* __restrict__ ob,
                             unsigned short* __restrict__ oc) {
  int i = blockIdx.x * blockDim.x + threadIdx.x;
  int stride = gridDim.x * blockDim.x;
  int total = na4 + nb4 + nc4;
  for (; i < total; i += stride) {
    const float4* src; ushort4* dst; int j;
    if (i < na4)            { src = (const float4*)a; dst = (ushort4*)oa; j = i; }
    else if (i < na4 + nb4) { src = (const float4*)b; dst = (ushort4*)ob; j = i - na4; }
    else                    { src = (const float4*)c; dst = (ushort4*)oc; j = i - na4 - nb4; }
    float4 v = src[j];
    ushort4 o;
    o.x = f2bf(v.x); o.y = f2bf(v.y); o.z = f2bf(v.z); o.w = f2bf(v.w);
    dst[j] = o;
  }
}

// ---------------- GEMM C = A * B^T  (A:[M,K] bf16, B:[N,K] bf16) ----------------
// BM x 128 tile, BK=32, 256 threads (4 waves, 2x2), 2-phase double-buffered:
// stage(t+1) issued BEFORE compute(t); single __syncthreads at END of iter
// (per-wave vmcnt(0) then barrier => all waves' prefetch visible: race-free).
template <int NP>
__device__ __forceinline__ void stage_tile(const unsigned short* g, int ld,
                                           unsigned short* ldsbase, int tid) {
#pragma unroll
  for (int p = 0; p < NP; ++p) {
    int j = p * 256 + tid;                 // 16B chunk index
    int row = j >> 2, cc = (j & 3) << 3;   // 4 chunks per 32-elem row
    const unsigned short* ga = g + (size_t)row * ld + cc;
    unsigned short* la = ldsbase + p * 2048 + (tid >> 6) * 512;  // wave-uniform
    __builtin_amdgcn_global_load_lds((gas_ptr)ga, (las_ptr)la, 16, 0, 0);
  }
}

// EPI 0: QKV epilogue — Q(scaled)/K -> qkb [4096][1536]; V -> LDS-transposed V^T
// EPI 1: f32 out.  Grid: 1-D, XCD-partitioned, y-fastest within XCD chunk.
template <int BM, int EPI, int NY, int PERX>
__launch_bounds__(256, EPI == 0 ? 3 : 4)
__global__ void gemm_bt(const unsigned short* __restrict__ A,
                        const unsigned short* __restrict__ B,
                        int K,
                        unsigned short* __restrict__ obf,
                        unsigned short* __restrict__ vt,
                        float* __restrict__ ofp,
                        const float* __restrict__ sptr) {
  constexpr int MI = BM / 32;
  constexpr int ABUF = BM * 32;            // shorts per A tile
  constexpr int BUF = ABUF + 4096;         // shorts per stage buffer (A+B)
  constexpr int LDS_SH = 2 * BUF;
  constexpr int TR_SH = (EPI == 0) ? 128 * 130 : 0;   // transpose buf, shorts
  constexpr int TOT = LDS_SH > TR_SH ? LDS_SH : TR_SH;
  __shared__ __attribute__((aligned(16))) unsigned short smem[TOT];
  int tid = threadIdx.x;
  int lane = tid & 63, wave = tid >> 6;
  // XCD partition: blocks L%8==k -> XCD k get a contiguous y-fastest chunk
  int L = blockIdx.x;
  int t0 = (L & 7) * PERX + (L >> 3);
  int row0 = (t0 / NY) * BM, col0 = (t0 % NY) * 128;
  int wr = (wave >> 1) * (BM / 2), wc = (wave & 1) * 64;
  int la = lane & 15, lb = lane >> 4;
  f32x4 acc[MI][4] = {};

  const unsigned short* Abase = A + (size_t)row0 * K;
  const unsigned short* Bbase = B + (size_t)col0 * K;
  stage_tile<BM / 64>(Abase, K, smem, tid);
  stage_tile<2>(Bbase, K, smem + ABUF, tid);
  __syncthreads();                    // tile 0 landed (vmcnt(0) + barrier)
  int cur = 0;
  int nt = K >> 5;
  for (int t = 0; t < nt; ++t) {
    if (t + 1 < nt) {                 // prefetch next tile into other buffer
      stage_tile<BM / 64>(Abase + (t + 1) * 32, K, smem + (cur ^ 1) * BUF, tid);
      stage_tile<2>(Bbase + (t + 1) * 32, K, smem + (cur ^ 1) * BUF + ABUF, tid);
    }
    unsigned short* lds = smem + cur * BUF;
    short8 af[MI], bfr[4];
#pragma unroll
    for (int i = 0; i < MI; ++i)
      af[i] = *(const short8*)&lds[(wr + i * 16 + la) * 32 + lb * 8];
#pragma unroll
    for (int j = 0; j < 4; ++j)
      bfr[j] = *(const short8*)&lds[ABUF + (wc + j * 16 + la) * 32 + lb * 8];
#pragma unroll
    for (int i = 0; i < MI; ++i)
#pragma unroll
      for (int j = 0; j < 4; ++j)
        acc[i][j] = __builtin_amdgcn_mfma_f32_16x16x32_bf16(af[i], bfr[j], acc[i][j], 0, 0, 0);
    __syncthreads();                  // prefetch landed + all reads of cur done
    cur ^= 1;
  }

  // epilogue: C/D layout col=lane&15, row=(lane>>4)*4+r  [m89-verified]
  if (EPI == 0 && col0 >= 1536) {
    // ---- V block: transpose via padded LDS, coalesced V^T writes ----
#pragma unroll
    for (int i = 0; i < MI; ++i)
#pragma unroll
      for (int j = 0; j < 4; ++j)
#pragma unroll
        for (int r = 0; r < 4; ++r)
          smem[(wr + i * 16 + lb * 4 + r) * 130 + (wc + j * 16 + la)] =
              f2bf(acc[i][j][r]);
    __syncthreads();
    int bb = row0 >> 11, t0r = row0 & 2047;
    int cl = tid >> 1, half = tid & 1;                 // cl: 0..127 col of C
    int vcol = col0 - 1536 + cl;
    int h = vcol >> 6, d = vcol & 63;
    unsigned short* dst =
        vt + ((size_t)(bb * NH + h) * 64 + d) * T_SEQ + t0r + half * 64;
#pragma unroll
    for (int j = 0; j < 8; ++j) {
      short8 v8;
#pragma unroll
      for (int e = 0; e < 8; ++e)
        v8[e] = (short)smem[(half * 64 + j * 8 + e) * 130 + cl];
      *(short8*)(dst + j * 8) = v8;
    }
    return;
  }

  float qs = 0.f;
  if (EPI == 0)
    qs = sptr[0] * 7.624618986159398f /*ln(2048)*/ * 0.125f /*1/sqrt(hd)*/
         * 1.4426950408889634f /*log2(e): exp2 domain*/;
#pragma unroll
  for (int i = 0; i < MI; ++i) {
    int gr0 = row0 + wr + i * 16 + lb * 4;
#pragma unroll
    for (int j = 0; j < 4; ++j) {
      int gc = col0 + wc + j * 16 + la;
#pragma unroll
      for (int r = 0; r < 4; ++r) {
        float v = acc[i][j][r];
        int rr = gr0 + r;
        if (EPI == 0) {
          obf[(size_t)rr * QK_LD + gc] = f2bf(gc < 768 ? v * qs : v);
        } else {
          ofp[(size_t)rr * C_DIM + gc] = v;
        }
      }
    }
  }
}

// ---------------- Flash attention, block-causal n=64, split-K chunks --------
// No max subtraction (exp2-domain scores bounded ~|15|: f32-safe); lsum
// deferred to one post-loop reduce. XCD partition: each XCD owns 3 heads
// (1.5 MB K/V working set -> L2-resident). qi<16: single chunk, final bf16
// written directly. qi>=16: two chunks -> f32 partial slots (both always
// written -> no zero pass), combined by norm_kernel.
__device__ __forceinline__ void attn_stage(const unsigned short* kg,
                                           const unsigned short* vg,
                                           char* kbuf, int wave, int lane) {
  int l3 = lane >> 3;
  int cg = ((lane & 7) ^ l3) << 4;  // swizzled source chunk byte offset
#pragma unroll
  for (int q = 0; q < 2; ++q) {
    int rk = q * 32 + wave * 8 + l3;                 // row within 64-row tile
    const unsigned short* ka = kg + (size_t)rk * QK_LD + (cg >> 1);
    char* kl = kbuf + (q * 32 + wave * 8) * 128;     // wave-uniform dest
    __builtin_amdgcn_global_load_lds((gas_ptr)ka, (las_ptr)kl, 16, 0, 0);
    const unsigned short* va = vg + (size_t)rk * T_SEQ + (cg >> 1);
    char* vl = kbuf + 8192 + (q * 32 + wave * 8) * 128;
    __builtin_amdgcn_global_load_lds((gas_ptr)va, (las_ptr)vl, 16, 0, 0);
  }
}

__launch_bounds__(256, 4)
__global__ void attn_kernel(const unsigned short* __restrict__ qkb,
                            const unsigned short* __restrict__ vt,
                            float* __restrict__ yp,     // [2][24][2048][64]
                            float* __restrict__ lsp,    // [2][24][2048]
                            unsigned short* __restrict__ yb) {
  __shared__ __attribute__((aligned(16))) char smem[2 * 16384 + 8192];

  int tid = threadIdx.x, lane = tid & 63, wave = tid >> 6;
  int la = lane & 15, lb = lane >> 4;
  // XCD partition: L%8 = XCD; each XCD owns bh in [3*xcd, 3*xcd+3)
  int L = blockIdx.x;                  // 0..1151
  int ixcd = L >> 3;                   // 0..143
  int bh = (L & 7) * 3 + ixcd / 48;
  int xx = 47 - (ixcd % 48);           // heavy chunks first within XCD
  int qi, cch;
  if (xx < 16) { qi = xx; cch = 0; }
  else         { int t = xx - 16; qi = 16 + (t >> 1); cch = t & 1; }
  int kt0 = cch * 16;
  int kt1 = min(qi, kt0 + 15);
  int b = bh / NH, h = bh - b * NH;

  // Q fragments in registers (A-operand: row=lane&15, k=(lane>>4)*8)
  const unsigned short* qbase =
      qkb + ((size_t)(b * T_SEQ + qi * 64 + wave * 16 + la)) * QK_LD + h * HD;
  short8 qf0 = *(const short8*)(qbase + lb * 8);
  short8 qf1 = *(const short8*)(qbase + 32 + lb * 8);
  asm volatile("" :: "v"(qf0), "v"(qf1));   // materialize before prefetch loop

  f32x4 y[4] = {};
  float ls[4] = {0.f, 0.f, 0.f, 0.f};

  const unsigned short* kg0 = qkb + (size_t)b * T_SEQ * QK_LD + 768 + h * HD;
  const unsigned short* vg0 = vt + (size_t)bh * 64 * T_SEQ;
  char* pw = smem + 32768 + wave * 2048;

  attn_stage(kg0 + (size_t)kt0 * 64 * QK_LD, vg0 + kt0 * 64, smem, wave, lane);
  int cur = 0;

  for (int kt = kt0; kt <= kt1; ++kt) {
    asm volatile("" ::: "memory");
    __builtin_amdgcn_s_barrier();            // done reading buf[cur^1]
    if (kt < kt1) {
      attn_stage(kg0 + (size_t)(kt + 1) * 64 * QK_LD, vg0 + (kt + 1) * 64,
                 smem + ((cur ^ 1) * 16384), wave, lane);
      asm volatile("s_waitcnt vmcnt(4)" ::: "memory");
    } else {
      asm volatile("s_waitcnt vmcnt(0)" ::: "memory");
    }
    __builtin_amdgcn_s_barrier();            // buf[cur] visible from all waves
    asm volatile("" ::: "memory");
    __builtin_amdgcn_sched_barrier(0);

    char* kl = smem + cur * 16384;
    char* vl = kl + 8192;

    // S = Q K^T (pre-scaled, exp2 domain). S frag: col(k)=la, row(q)=4*lb+r
    f32x4 s[4] = {};
    __builtin_amdgcn_s_setprio(1);
#pragma unroll
    for (int fk = 0; fk < 4; ++fk) {
      int row = fk * 16 + la;
      {
        int off = (row * 128 + 0 * 64 + lb * 16) ^ ((row & 7) << 4);
        short8 kf = *(const short8*)(kl + off);
        s[fk] = __builtin_amdgcn_mfma_f32_16x16x32_bf16(qf0, kf, s[fk], 0, 0, 0);
      }
      {
        int off = (row * 128 + 1 * 64 + lb * 16) ^ ((row & 7) << 4);
        short8 kf = *(const short8*)(kl + off);
        s[fk] = __builtin_amdgcn_mfma_f32_16x16x32_bf16(qf1, kf, s[fk], 0, 0, 0);
      }
    }
    __builtin_amdgcn_s_setprio(0);

    // p = exp2(S); accumulate per-lane lsum; write P to per-wave LDS
#pragma unroll
    for (int fk = 0; fk < 4; ++fk)
#pragma unroll
      for (int r = 0; r < 4; ++r) {
        float p = __builtin_amdgcn_exp2f(s[fk][r]);
        s[fk][r] = p;
        ls[r] += p;
        int row = lb * 4 + r;
        int off = (row * 128 + (fk * 16 + la) * 2) ^ ((row & 7) << 4);
        *(unsigned short*)(pw + off) = f2bf(p);
      }

    // Y += P V : A-frags from p_lds, B-frags from v_lds
    short8 pa[2];
#pragma unroll
    for (int ch = 0; ch < 2; ++ch) {
      int off = (la * 128 + ch * 64 + lb * 16) ^ ((la & 7) << 4);
      pa[ch] = *(const short8*)(pw + off);
    }
    __builtin_amdgcn_s_setprio(1);
#pragma unroll
    for (int fd = 0; fd < 4; ++fd) {
      int row = fd * 16 + la;
#pragma unroll
      for (int ch = 0; ch < 2; ++ch) {
        int off = (row * 128 + ch * 64 + lb * 16) ^ ((row & 7) << 4);
        short8 vf = *(const short8*)(vl + off);
        y[fd] = __builtin_amdgcn_mfma_f32_16x16x32_bf16(pa[ch], vf, y[fd], 0, 0, 0);
      }
    }
    __builtin_amdgcn_s_setprio(0);

    cur ^= 1;
  }

  // reduce lsum over the 16 k-col lanes (full row sum for this chunk)
#pragma unroll
  for (int r = 0; r < 4; ++r) {
    float v = ls[r];
    v += __shfl_xor(v, 1); v += __shfl_xor(v, 2);
    v += __shfl_xor(v, 4); v += __shfl_xor(v, 8);
    ls[r] = v;
  }
  int trow = qi * 64 + wave * 16 + lb * 4;   // + r

  if (qi < 16) {
    // single chunk == full row: write final bf16 directly
    float inv[4];
#pragma unroll
    for (int r = 0; r < 4; ++r) inv[r] = 1.0f / ls[r];
#pragma unroll
    for (int fd = 0; fd < 4; ++fd)
#pragma unroll
      for (int r = 0; r < 4; ++r) {
        int rowg = b * T_SEQ + trow + r;
        int colg = h * HD + fd * 16 + la;
        yb[(size_t)rowg * C_DIM + colg] = f2bf(y[fd][r] * inv[r]);
      }
  } else {
    // f32 partials to slot cch (both slots always written for qi>=16)
    size_t slotbase = (size_t)cch * (24 * 2048);
    if (la == 0) {
#pragma unroll
      for (int r = 0; r < 4; ++r)
        lsp[slotbase + (size_t)bh * 2048 + trow + r] = ls[r];
    }
    float* ydst = yp + (slotbase + (size_t)bh * 2048) * 64;
#pragma unroll
    for (int fd = 0; fd < 4; ++fd)
#pragma unroll
      for (int r = 0; r < 4; ++r)
        ydst[(size_t)(trow + r) * 64 + fd * 16 + la] = y[fd][r];
  }
}

// ------- normalize + pack (qi>=16 rows only): yb = bf16((yp0+yp1)/(l0+l1)) --
__global__ void norm_kernel(const float* __restrict__ yp,
                            const float* __restrict__ lsp,
                            unsigned short* __restrict__ yb) {
  int gid = blockIdx.x * blockDim.x + threadIdx.x;  // 24*1024*16
  int dq = gid & 15;
  int rloc = gid >> 4;           // bh*1024 + (t-1024)
  int bh = rloc >> 10, t = 1024 + (rloc & 1023);
  int row = bh * 2048 + t;
  int b = bh / NH, h = bh - b * NH;
  float denom = lsp[row] + lsp[24 * 2048 + row];
  float inv = 1.0f / denom;
  float4 y0 = ((const float4*)yp)[row * 16 + dq];
  float4 y1 = ((const float4*)yp)[(24 * 2048 * 16) + row * 16 + dq];
  ushort4 o;
  o.x = f2bf((y0.x + y1.x) * inv);
  o.y = f2bf((y0.y + y1.y) * inv);
  o.z = f2bf((y0.z + y1.z) * inv);
  o.w = f2bf((y0.w + y1.w) * inv);
  ((ushort4*)yb)[(size_t)(b * T_SEQ + t) * 192 + h * 16 + dq] = o;
}

// ---------------- launch ----------------
extern "C" void kernel_launch(void* const* d_in, const int* in_sizes, int n_in,
                              void* d_out, int out_size, void* d_ws, size_t ws_size,
                              hipStream_t stream) {
  const float* x = (const float*)d_in[0];        // [2,2048,768]
  const float* attn_w = (const float*)d_in[1];   // [2304,768]
  const float* proj_w = (const float*)d_in[2];   // [768,768]
  const float* s = (const float*)d_in[3];        // [1]
  float* out = (float*)d_out;                    // [2,2048,768] f32

  char* ws = (char*)d_ws;
  unsigned short* xb  = (unsigned short*)(ws);                    //  6,291,456
  unsigned short* wab = (unsigned short*)(ws + 6291456);          //  3,538,944
  unsigned short* wpb = (unsigned short*)(ws + 9830400);          //  1,179,648
  unsigned short* qkb = (unsigned short*)(ws + 11010048);         // 12,582,912
  unsigned short* vtb = (unsigned short*)(ws + 23592960);         //  6,291,456
  unsigned short* yb  = (unsigned short*)(ws + 29884416);         //  6,291,456
  float*          yp  = (float*)(ws + 36175872);                  // 25,165,824 (2 slots)
  float*          lsp = (float*)(ws + 61341696);                  //    393,216 (2 slots)
  // total 61,734,912 B

  cast3_kernel<<<2048, 256, 0, stream>>>(x, 3145728 / 4, attn_w, 1769472 / 4,
                                         proj_w, 589824 / 4, xb, wab, wpb);

  // QKV: [4096,768] x [2304,768]^T -> Q/K packed (LD 1536) + V^T
  // 576 blocks = 8 XCD x 72 (y-fastest: 4 A-panel rows + shared B per XCD)
  gemm_bt<128, 0, 18, 72><<<576, 256, 0, stream>>>(xb, wab, 768, qkb, vtb, nullptr, s);

  // attention: 1152 blocks = 8 XCD x (3 heads x 48 chunks)
  attn_kernel<<<1152, 256, 0, stream>>>(qkb, vtb, yp, lsp, yb);

  // combine qi>=16 partials -> yb bf16
  norm_kernel<<<1536, 256, 0, stream>>>(yp, lsp, yb);

  // proj: [4096,768] x [768,768]^T -> f32 out; 384 blocks = 8 XCD x 48
  gemm_bt<64, 1, 6, 48><<<384, 256, 0, stream>>>(yb, wpb, 768, nullptr, nullptr, out, nullptr);
}